// Round 1
// baseline (477.815 us; speedup 1.0000x reference)
//
#include <hip/hip_runtime.h>
#include <hip/hip_bf16.h>
#include <math.h>

#define B_ROWS 1024
#define DDIM   512
#define CN     51332
#define CPAD   51456   /* 402 * 128 */
#define EPSF   1e-3f
#define SCALE  64.0f

typedef unsigned short ushort_t;
typedef short bf16x8 __attribute__((ext_vector_type(8)));   // 8 bf16 (4 VGPRs)
typedef float f32x4  __attribute__((ext_vector_type(4)));   // 4 fp32 acc
typedef unsigned short us8 __attribute__((ext_vector_type(8)));
typedef unsigned short us4 __attribute__((ext_vector_type(4)));

static __device__ __forceinline__ unsigned short f2bf(float f) {
    // round-to-nearest-even fp32 -> bf16 (inputs are finite)
    unsigned int u = __float_as_uint(f);
    u += 0x7fffu + ((u >> 16) & 1u);
    return (unsigned short)(u >> 16);
}

// Pass 1: column sum-of-squares partials + bf16 cast + transpose to [CPAD, DDIM]
__global__ void colpass(const float* __restrict__ kern, ushort_t* __restrict__ kbT,
                        float* __restrict__ partials) {
    const int c  = blockIdx.x * 256 + threadIdx.x;   // column (CPAD covered exactly)
    const int dc = blockIdx.y;                       // d-chunk 0..3
    const int d0 = dc * 128;
    const bool valid = (c < CN);
    float s = 0.f;
    for (int d = d0; d < d0 + 128; d += 8) {
        us8 pk;
#pragma unroll
        for (int j = 0; j < 8; ++j) {
            float v = valid ? kern[(size_t)(d + j) * CN + c] : 0.f;
            s += v * v;
            pk[j] = f2bf(v);
        }
        *(us8*)&kbT[(size_t)c * DDIM + d] = pk;      // 16B store, kbT[c][d..d+7]
    }
    partials[(size_t)dc * CPAD + c] = s;
}

__global__ void finnorm(const float* __restrict__ partials, float* __restrict__ inv_norm) {
    const int c = blockIdx.x * 256 + threadIdx.x;
    float s = partials[c] + partials[CPAD + c] + partials[2 * CPAD + c] + partials[3 * CPAD + c];
    inv_norm[c] = 1.0f / fmaxf(sqrtf(s), 1e-5f);
}

__global__ void embcast(const float* __restrict__ emb, ushort_t* __restrict__ embb) {
    const int t = blockIdx.x * 256 + threadIdx.x;    // 4 elems/thread
    const float4 v = ((const float4*)emb)[t];
    us4 o; o[0] = f2bf(v.x); o[1] = f2bf(v.y); o[2] = f2bf(v.z); o[3] = f2bf(v.w);
    *(us4*)&embb[(size_t)t * 4] = o;
}

// 128x128 tile bf16 MFMA GEMM: out[m, n] = clip((embb[m,:] . kbT[n,:]) * inv_norm[n]) * 64
__global__ __launch_bounds__(256) void gemm_kernel(
        const ushort_t* __restrict__ embb, const ushort_t* __restrict__ kbT,
        const float* __restrict__ inv_norm, float* __restrict__ out) {
    __shared__ ushort_t As[128 * 64];   // [m][k] k-contiguous
    __shared__ ushort_t Bs[128 * 64];   // [n][k] k-contiguous
    const int tid  = threadIdx.x;
    const int lane = tid & 63;
    const int wave = tid >> 6;
    const int wm = wave & 1, wn = wave >> 1;
    const int m0 = blockIdx.x * 128;
    const int n0 = blockIdx.y * 128;
    const int r8 = lane >> 3, c8 = lane & 7;   // staging lane -> (row-in-8, 16B chunk)
    const int lm = lane & 15;                  // MFMA m/n within 16
    const int lq = lane >> 4;                  // MFMA quad

    f32x4 acc[4][4];
#pragma unroll
    for (int i = 0; i < 4; ++i)
#pragma unroll
        for (int j = 0; j < 4; ++j)
            acc[i][j] = (f32x4){0.f, 0.f, 0.f, 0.f};

    for (int kt = 0; kt < 8; ++kt) {
        const int k0 = kt * 64;
        // stage A and B tiles: each wave issues 4+4 global_load_lds (16B/lane, 8 rows each)
#pragma unroll
        for (int it = 0; it < 4; ++it) {
            const int row = wave * 32 + it * 8;
            const ushort_t* gA = embb + (size_t)(m0 + row + r8) * DDIM + k0 + c8 * 8;
            __builtin_amdgcn_global_load_lds((__attribute__((address_space(1))) void*)gA,
                (__attribute__((address_space(3))) void*)&As[row * 64], 16, 0, 0);
            const ushort_t* gB = kbT + (size_t)(n0 + row + r8) * DDIM + k0 + c8 * 8;
            __builtin_amdgcn_global_load_lds((__attribute__((address_space(1))) void*)gB,
                (__attribute__((address_space(3))) void*)&Bs[row * 64], 16, 0, 0);
        }
        __syncthreads();
#pragma unroll
        for (int ks = 0; ks < 64; ks += 32) {
            bf16x8 a[4], b[4];
#pragma unroll
            for (int i = 0; i < 4; ++i)
                a[i] = *(const bf16x8*)&As[(wm * 64 + i * 16 + lm) * 64 + ks + lq * 8];
#pragma unroll
            for (int j = 0; j < 4; ++j)
                b[j] = *(const bf16x8*)&Bs[(wn * 64 + j * 16 + lm) * 64 + ks + lq * 8];
#pragma unroll
            for (int i = 0; i < 4; ++i)
#pragma unroll
                for (int j = 0; j < 4; ++j)
                    acc[i][j] = __builtin_amdgcn_mfma_f32_16x16x32_bf16(a[i], b[j], acc[i][j], 0, 0, 0);
        }
        __syncthreads();
    }

    // Epilogue: cosine = acc * inv_norm[col]; out = clip(cosine, +-0.999) * 64
#pragma unroll
    for (int j = 0; j < 4; ++j) {
        const int col = n0 + wn * 64 + j * 16 + lm;
        const bool ok = col < CN;
        const float inv = ok ? inv_norm[col] : 0.f;
#pragma unroll
        for (int i = 0; i < 4; ++i) {
            const int row0 = m0 + wm * 64 + i * 16 + lq * 4;
#pragma unroll
            for (int r = 0; r < 4; ++r) {
                float v = acc[i][j][r] * inv;
                v = fminf(fmaxf(v, -(1.0f - EPSF)), 1.0f - EPSF) * SCALE;
                if (ok) out[(size_t)(row0 + r) * CN + col] = v;
            }
        }
    }
}

// Label-column fixup: arccos margin path on exactly B_ROWS elements
__global__ void fixup(const float* __restrict__ norms, const int* __restrict__ label,
                      float* __restrict__ out) {
    const int b = blockIdx.x * 256 + threadIdx.x;
    if (b >= B_ROWS) return;
    const int c = label[b];
    const float safe = fminf(fmaxf(norms[b], 1e-3f), 100.0f);
    const float ms = fminf(fmaxf(safe / (100.0f + 1e-3f) * 0.333f, -1.0f), 1.0f);
    const size_t idx = (size_t)b * CN + c;
    const float cosv = out[idx] * (1.0f / SCALE);        // recover clipped cosine
    float theta = acosf(cosv) + 0.5f * ms;               // + M*ms at label
    theta = fminf(fmaxf(theta, EPSF), 3.14159265358979f - EPSF);
    out[idx] = (cosf(theta) - (0.5f - 0.5f * ms)) * SCALE;  // - (HEAD_B - M*ms), * S
}

extern "C" void kernel_launch(void* const* d_in, const int* in_sizes, int n_in,
                              void* d_out, int out_size, void* d_ws, size_t ws_size,
                              hipStream_t stream) {
    const float* emb   = (const float*)d_in[0];
    const float* norms = (const float*)d_in[1];
    const float* kern  = (const float*)d_in[2];
    const int*   label = (const int*)d_in[3];
    float* out = (float*)d_out;

    char* ws = (char*)d_ws;
    ushort_t* kbT = (ushort_t*)ws;                           // CPAD*DDIM*2 = 52,690,944 B
    size_t off = (size_t)CPAD * DDIM * 2;
    ushort_t* embb = (ushort_t*)(ws + off); off += (size_t)B_ROWS * DDIM * 2;
    float* inv_norm = (float*)(ws + off);   off += (size_t)CPAD * 4;
    float* partials = (float*)(ws + off);   // 4*CPAD*4 B ; total ~54.8 MB

    colpass<<<dim3(CPAD / 256, 4), 256, 0, stream>>>(kern, kbT, partials);
    embcast<<<dim3((B_ROWS * DDIM / 4) / 256), 256, 0, stream>>>(emb, embb);
    finnorm<<<dim3(CPAD / 256), 256, 0, stream>>>(partials, inv_norm);
    gemm_kernel<<<dim3(B_ROWS / 128, CPAD / 128), 256, 0, stream>>>(embb, kbT, inv_norm, out);
    fixup<<<dim3(B_ROWS / 256), 256, 0, stream>>>(norms, label, out);
}

// Round 2
// 455.718 us; speedup vs baseline: 1.0485x; 1.0485x over previous
//
#include <hip/hip_runtime.h>
#include <hip/hip_bf16.h>
#include <math.h>

#define B_ROWS 1024
#define DDIM   512
#define CN     51332
#define CPAD   51456   /* 402 * 128 */
#define EPSF   1e-3f
#define SCALE  64.0f

typedef unsigned short ushort_t;
typedef short bf16x8 __attribute__((ext_vector_type(8)));   // 8 bf16 (4 VGPRs)
typedef float f32x4  __attribute__((ext_vector_type(4)));   // 4 fp32 acc
typedef unsigned short us8 __attribute__((ext_vector_type(8)));
typedef unsigned short us4 __attribute__((ext_vector_type(4)));

static __device__ __forceinline__ unsigned short f2bf(float f) {
    // round-to-nearest-even fp32 -> bf16 (inputs are finite)
    unsigned int u = __float_as_uint(f);
    u += 0x7fffu + ((u >> 16) & 1u);
    return (unsigned short)(u >> 16);
}

// Pass 1: column sum-of-squares partials + bf16 cast + transpose to [CPAD, DDIM]
__global__ void colpass(const float* __restrict__ kern, ushort_t* __restrict__ kbT,
                        float* __restrict__ partials) {
    const int c  = blockIdx.x * 256 + threadIdx.x;   // column (CPAD covered exactly)
    const int dc = blockIdx.y;                       // d-chunk 0..3
    const int d0 = dc * 128;
    const bool valid = (c < CN);
    float s = 0.f;
    for (int d = d0; d < d0 + 128; d += 8) {
        us8 pk;
#pragma unroll
        for (int j = 0; j < 8; ++j) {
            float v = valid ? kern[(size_t)(d + j) * CN + c] : 0.f;
            s += v * v;
            pk[j] = f2bf(v);
        }
        *(us8*)&kbT[(size_t)c * DDIM + d] = pk;      // 16B store, kbT[c][d..d+7]
    }
    partials[(size_t)dc * CPAD + c] = s;
}

__global__ void finnorm(const float* __restrict__ partials, float* __restrict__ inv_norm) {
    const int c = blockIdx.x * 256 + threadIdx.x;
    float s = partials[c] + partials[CPAD + c] + partials[2 * CPAD + c] + partials[3 * CPAD + c];
    inv_norm[c] = 1.0f / fmaxf(sqrtf(s), 1e-5f);
}

__global__ void embcast(const float* __restrict__ emb, ushort_t* __restrict__ embb) {
    const int t = blockIdx.x * 256 + threadIdx.x;    // 4 elems/thread
    const float4 v = ((const float4*)emb)[t];
    us4 o; o[0] = f2bf(v.x); o[1] = f2bf(v.y); o[2] = f2bf(v.z); o[3] = f2bf(v.w);
    *(us4*)&embb[(size_t)t * 4] = o;
}

// 128x128 tile bf16 MFMA GEMM: out[m, n] = clip((embb[m,:] . kbT[n,:]) * inv_norm[n]) * 64
// XCD-swizzled 1D grid; LDS-staged coalesced epilogue.
__global__ __launch_bounds__(256) void gemm_kernel(
        const ushort_t* __restrict__ embb, const ushort_t* __restrict__ kbT,
        const float* __restrict__ inv_norm, float* __restrict__ out) {
    __shared__ ushort_t smem[2 * 128 * 64];          // As | Bs ; epilogue reuses as float[64][128]
    ushort_t* As = smem;                             // [m][k] k-contiguous
    ushort_t* Bs = smem + 128 * 64;                  // [n][k] k-contiguous
    float*    Es = (float*)smem;                     // 64 x 128 fp32 = 32 KB

    // XCD swizzle: keep each stripe's 8 m-blocks consecutive within one XCD
    // (assumes round-robin block->XCD by flat id % 8; if mapping differs this
    // is perf-neutral, never wrong).
    const int bid = blockIdx.x;                      // 0..3215
    const int u   = (bid & 7) * 402 + (bid >> 3);    // unit within presumed XCD ordering
    const int m0  = (u & 7) * 128;                   // m tile 0..7
    const int n0  = (u >> 3) * 128;                  // n stripe 0..401

    const int tid  = threadIdx.x;
    const int lane = tid & 63;
    const int wave = tid >> 6;
    const int wm = wave & 1, wn = wave >> 1;
    const int r8 = lane >> 3, c8 = lane & 7;   // staging lane -> (row-in-8, 16B chunk)
    const int lm = lane & 15;                  // MFMA m/n within 16
    const int lq = lane >> 4;                  // MFMA quad

    f32x4 acc[4][4];
#pragma unroll
    for (int i = 0; i < 4; ++i)
#pragma unroll
        for (int j = 0; j < 4; ++j)
            acc[i][j] = (f32x4){0.f, 0.f, 0.f, 0.f};

    for (int kt = 0; kt < 8; ++kt) {
        const int k0 = kt * 64;
#pragma unroll
        for (int it = 0; it < 4; ++it) {
            const int row = wave * 32 + it * 8;
            const ushort_t* gA = embb + (size_t)(m0 + row + r8) * DDIM + k0 + c8 * 8;
            __builtin_amdgcn_global_load_lds((__attribute__((address_space(1))) void*)gA,
                (__attribute__((address_space(3))) void*)&As[row * 64], 16, 0, 0);
            const ushort_t* gB = kbT + (size_t)(n0 + row + r8) * DDIM + k0 + c8 * 8;
            __builtin_amdgcn_global_load_lds((__attribute__((address_space(1))) void*)gB,
                (__attribute__((address_space(3))) void*)&Bs[row * 64], 16, 0, 0);
        }
        __syncthreads();
#pragma unroll
        for (int ks = 0; ks < 64; ks += 32) {
            bf16x8 a[4], b[4];
#pragma unroll
            for (int i = 0; i < 4; ++i)
                a[i] = *(const bf16x8*)&As[(wm * 64 + i * 16 + lm) * 64 + ks + lq * 8];
#pragma unroll
            for (int j = 0; j < 4; ++j)
                b[j] = *(const bf16x8*)&Bs[(wn * 64 + j * 16 + lm) * 64 + ks + lq * 8];
#pragma unroll
            for (int i = 0; i < 4; ++i)
#pragma unroll
                for (int j = 0; j < 4; ++j)
                    acc[i][j] = __builtin_amdgcn_mfma_f32_16x16x32_bf16(a[i], b[j], acc[i][j], 0, 0, 0);
        }
        __syncthreads();
    }

    // inv_norm for this wave's 4 column groups (col = n0 + wn*64 + j*16 + lm)
    float invn[4];
#pragma unroll
    for (int j = 0; j < 4; ++j) {
        const int col = n0 + wn * 64 + j * 16 + lm;
        invn[j] = (col < CN) ? inv_norm[col] : 0.f;
    }

    // Epilogue via LDS: two 64-row chunks; swizzled (col + row*4) % 128 to kill
    // bank conflicts; readback as f32x4 -> 512B-contiguous coalesced row stores.
#pragma unroll
    for (int half = 0; half < 2; ++half) {
        __syncthreads();
        if (wm == half) {
#pragma unroll
            for (int i = 0; i < 4; ++i)
#pragma unroll
                for (int j = 0; j < 4; ++j)
#pragma unroll
                    for (int r = 0; r < 4; ++r) {
                        const int row = i * 16 + lq * 4 + r;          // 0..63 local
                        const int col = wn * 64 + j * 16 + lm;        // 0..127
                        const int cs  = (col + row * 4) & 127;        // swizzle
                        float v = acc[i][j][r] * invn[j];
                        v = fminf(fmaxf(v, -(1.0f - EPSF)), 1.0f - EPSF) * SCALE;
                        Es[row * 128 + cs] = v;
                    }
        }
        __syncthreads();
#pragma unroll
        for (int it = 0; it < 8; ++it) {
            const int row = wave * 16 + it * 2 + (lane >> 5);   // 0..63 local
            const int uq  = lane & 31;                          // 16B unit (4 cols)
            const int us_ = (uq + row) & 31;                    // unswizzle
            const f32x4 v = *(const f32x4*)&Es[row * 128 + us_ * 4];
            const int grow = m0 + half * 64 + row;
            const int gcol = n0 + uq * 4;
            float* p = &out[(size_t)grow * CN + gcol];
            if (gcol + 3 < CN) {
                *(f32x4*)p = v;
            } else {
#pragma unroll
                for (int e = 0; e < 4; ++e)
                    if (gcol + e < CN) p[e] = v[e];
            }
        }
    }
}

// Label-column fixup: arccos margin path on exactly B_ROWS elements
__global__ void fixup(const float* __restrict__ norms, const int* __restrict__ label,
                      float* __restrict__ out) {
    const int b = blockIdx.x * 256 + threadIdx.x;
    if (b >= B_ROWS) return;
    const int c = label[b];
    const float safe = fminf(fmaxf(norms[b], 1e-3f), 100.0f);
    const float ms = fminf(fmaxf(safe / (100.0f + 1e-3f) * 0.333f, -1.0f), 1.0f);
    const size_t idx = (size_t)b * CN + c;
    const float cosv = out[idx] * (1.0f / SCALE);        // recover clipped cosine
    float theta = acosf(cosv) + 0.5f * ms;               // + M*ms at label
    theta = fminf(fmaxf(theta, EPSF), 3.14159265358979f - EPSF);
    out[idx] = (cosf(theta) - (0.5f - 0.5f * ms)) * SCALE;  // - (HEAD_B - M*ms), * S
}

extern "C" void kernel_launch(void* const* d_in, const int* in_sizes, int n_in,
                              void* d_out, int out_size, void* d_ws, size_t ws_size,
                              hipStream_t stream) {
    const float* emb   = (const float*)d_in[0];
    const float* norms = (const float*)d_in[1];
    const float* kern  = (const float*)d_in[2];
    const int*   label = (const int*)d_in[3];
    float* out = (float*)d_out;

    char* ws = (char*)d_ws;
    ushort_t* kbT = (ushort_t*)ws;                           // CPAD*DDIM*2 = 52,690,944 B
    size_t off = (size_t)CPAD * DDIM * 2;
    ushort_t* embb = (ushort_t*)(ws + off); off += (size_t)B_ROWS * DDIM * 2;
    float* inv_norm = (float*)(ws + off);   off += (size_t)CPAD * 4;
    float* partials = (float*)(ws + off);   // 4*CPAD*4 B ; total ~54.8 MB

    colpass<<<dim3(CPAD / 256, 4), 256, 0, stream>>>(kern, kbT, partials);
    embcast<<<dim3((B_ROWS * DDIM / 4) / 256), 256, 0, stream>>>(emb, embb);
    finnorm<<<dim3(CPAD / 256), 256, 0, stream>>>(partials, inv_norm);
    gemm_kernel<<<dim3(3216), 256, 0, stream>>>(embb, kbT, inv_norm, out);
    fixup<<<dim3(B_ROWS / 256), 256, 0, stream>>>(norms, label, out);
}